// Round 1
// baseline (232.513 us; speedup 1.0000x reference)
//
#include <hip/hip_runtime.h>
#include <cstdint>
#include <cstddef>

typedef float  f32x4 __attribute__((ext_vector_type(4)));
typedef short  s16x8 __attribute__((ext_vector_type(8)));

#define DEV __device__ __forceinline__

static constexpr int    DHW       = 32768;       // 8*64*64
static constexpr int    NTOK      = 65536;       // B*D*H*W
static constexpr int    KCB       = 4096;        // codebook size
static constexpr int    NCHUNK    = 64;          // 4096/64 codes per chunk
static constexpr int    CHUNK_BYTES = 16640;     // 8192 gh + 8192 gl + 256 e2
static constexpr size_t OUT_ELEMS = 4194304;     // 2*64*32768
static constexpr float  BIGC      = 512.0f;      // positivity bias for uint-compare
static constexpr float  TAU       = 0.015f;      // near-tie refinement threshold
static constexpr int    FLAG_CAP  = 2048;

// workspace byte offsets (all 256B aligned)
static constexpr size_t WS_PREP = 0;                          // 64*16640 = 1,064,960
static constexpr size_t WS_IDX  = 1064960;                    // 65536 * int
static constexpr size_t WS_PART = WS_IDX + 262144;            // 256 * float
static constexpr size_t WS_CNT  = WS_PART + 1024;             // int counter
static constexpr size_t WS_FLAG = WS_CNT + 256;               // FLAG_CAP * int

DEV unsigned f2bf(float f) {            // RNE float -> bf16 bits
  unsigned u = __float_as_uint(f);
  return (u + 0x7FFFu + ((u >> 16) & 1u)) >> 16;
}
DEV float bf2f(unsigned h) { return __uint_as_float(h << 16); }
DEV unsigned med3u(unsigned a, unsigned b, unsigned c) {
  unsigned r;
  asm("v_med3_u32 %0, %1, %2, %3" : "=v"(r) : "v"(a), "v"(b), "v"(c));
  return r;
}

// ---------------- Kernel A: pre-conv (t = pre_w@z + pre_b) + embedding prep ----
// t stored [C=64][NTOK] INSIDE d_out's out-region (overwritten later by k_post).
// prep: per 64-code chunk: gh(bf16 of -2e, XOR-swizzled rows), gl(residual), e2=512+||e||^2
__global__ __launch_bounds__(256) void k_pre(const float* __restrict__ z,
    const float* __restrict__ emb, const float* __restrict__ pw, const float* __restrict__ pb,
    float* __restrict__ dout, char* __restrict__ ws)
{
  const int blk = blockIdx.x, tid = threadIdx.x;
  if (blk == 0 && tid == 0) *(int*)(ws + WS_CNT) = 0;
  if (blk < 256) {
    float* t = dout;
    const int v = blk * 256 + tid;
    const int b = v >> 15, r = v & (DHW - 1);
    const float* zp = z + (size_t)b * 64 * DHW + r;
    float zr[64];
#pragma unroll
    for (int c2 = 0; c2 < 64; ++c2) zr[c2] = zp[(size_t)c2 * DHW];
    for (int c = 0; c < 64; ++c) {          // c uniform -> pre_w row via s_load
      float a = pb[c];
      const float* wr = pw + c * 64;
#pragma unroll
      for (int c2 = 0; c2 < 64; ++c2) a = fmaf(wr[c2], zr[c2], a);
      t[(size_t)c * NTOK + v] = a;          // coalesced across lanes
    }
  } else {
    const int tt = (blk - 256) * 256 + tid;  // 0..16383, 2 units each
#pragma unroll
    for (int uu = 0; uu < 2; ++uu) {
      const int u = tt * 2 + uu;
      const int k = u >> 3, j = u & 7;
      const float* ep = emb + (size_t)k * 64 + j * 8;
      unsigned hw[4], lw[4];
#pragma unroll
      for (int i = 0; i < 4; ++i) {
        float g0 = -2.0f * ep[2 * i], g1 = -2.0f * ep[2 * i + 1];
        unsigned h0 = f2bf(g0); unsigned l0 = f2bf(g0 - bf2f(h0));
        unsigned h1 = f2bf(g1); unsigned l1 = f2bf(g1 - bf2f(h1));
        hw[i] = h0 | (h1 << 16); lw[i] = l0 | (l1 << 16);
      }
      char* base = ws + WS_PREP + (size_t)(k >> 6) * CHUNK_BYTES;
      const int row = k & 63;
      const int off = row * 128 + ((j * 16) ^ ((row & 7) << 4));   // bank swizzle
      *(uint4*)(base + off)        = make_uint4(hw[0], hw[1], hw[2], hw[3]);
      *(uint4*)(base + 8192 + off) = make_uint4(lw[0], lw[1], lw[2], lw[3]);
      if (j == 0) {
        const float* er = emb + (size_t)k * 64;
        float s = 0.f;
#pragma unroll
        for (int c = 0; c < 64; ++c) s = fmaf(er[c], er[c], s);
        *(float*)(base + 16384 + row * 4) = s + BIGC;
      }
    }
  }
}

// ---------------- Kernel B: bf16x3 MFMA distance + argmin + loss partials ------
// 256 blocks x 512 thr (8 waves). Wave owns 32 tokens (2 col-fragments).
// Per chunk of 64 codes: acc[cf][tf] = (512+||e||^2) + (-2e).t  via 3 chained MFMAs.
__global__ __launch_bounds__(512, 2) void k_dist(const float* __restrict__ emb,
    float* __restrict__ dout, char* __restrict__ ws)
{
  __shared__ __align__(16) char smem[2 * CHUNK_BYTES + 64];
  const float* t = dout;                       // [64][NTOK]
  int*   idxw = (int*)(ws + WS_IDX);
  float* part = (float*)(ws + WS_PART);
  int*   cnt  = (int*)(ws + WS_CNT);
  int*   flg  = (int*)(ws + WS_FLAG);
  float* fidx = dout + OUT_ELEMS + 2;

  const int tid = threadIdx.x;
  const int w = tid >> 6, lane = tid & 63;
  const int l15 = lane & 15, grp = lane >> 4;
  const int tb = blockIdx.x * 256 + w * 32;

  // ---- load t fragments and split into bf16 hi/lo (held in registers) ----
  unsigned th_[2][2][4], tl_[2][2][4];         // [tf][ks][4 packed pairs]
#pragma unroll
  for (int tf = 0; tf < 2; ++tf) {
    const int tok = tb + tf * 16 + l15;
#pragma unroll
    for (int ks = 0; ks < 2; ++ks) {
      const float* tc = t + (size_t)(ks * 32 + grp * 8) * NTOK + tok;
      float f[8];
#pragma unroll
      for (int i = 0; i < 8; ++i) f[i] = tc[(size_t)i * NTOK];
#pragma unroll
      for (int i = 0; i < 4; ++i) {
        unsigned h0 = f2bf(f[2 * i]),     l0 = f2bf(f[2 * i]     - bf2f(h0));
        unsigned h1 = f2bf(f[2 * i + 1]), l1 = f2bf(f[2 * i + 1] - bf2f(h1));
        th_[tf][ks][i] = h0 | (h1 << 16);
        tl_[tf][ks][i] = l0 | (l1 << 16);
      }
    }
  }

  const char* prep = ws + WS_PREP;
  uint4 ra, rb; float re2 = 0.f;
  { // preload chunk 0 straight into LDS buf0
    const uint4* s0 = (const uint4*)prep;
    ra = s0[tid]; rb = s0[512 + tid];
    if (tid < 64) re2 = *(const float*)(prep + 16384 + tid * 4);
    uint4* d = (uint4*)smem;
    d[tid] = ra; d[512 + tid] = rb;
    if (tid < 64) *(float*)(smem + 16384 + tid * 4) = re2;
  }
  __syncthreads();

  unsigned u1[2] = {0x7f800000u, 0x7f800000u};   // best (masked|wid) key
  unsigned u2[2] = {0x7f800000u, 0x7f800000u};   // 2nd best key (gating)
  int c1[2] = {0, 0};                            // winning chunk

  for (int c = 0; c < NCHUNK; ++c) {
    const char* L = smem + (c & 1) * CHUNK_BYTES;
    const bool more = (c + 1 < NCHUNK);
    if (more) {                                  // issue next-chunk loads early (T14)
      const char* pn = prep + (size_t)(c + 1) * CHUNK_BYTES;
      const uint4* sn = (const uint4*)pn;
      ra = sn[tid]; rb = sn[512 + tid];
      if (tid < 64) re2 = *(const float*)(pn + 16384 + tid * 4);
    }
    f32x4 acc[4][2];
#pragma unroll
    for (int cf = 0; cf < 4; ++cf) {             // seed with 512+||e||^2
      f32x4 e2v = *(const f32x4*)(L + 16384 + cf * 64 + grp * 16);
      acc[cf][0] = e2v; acc[cf][1] = e2v;
    }
#pragma unroll
    for (int ks = 0; ks < 2; ++ks) {
      s16x8 tva[2], tvl[2];
#pragma unroll
      for (int tf = 0; tf < 2; ++tf) {
        union { unsigned u[4]; s16x8 v; } xh, xl;
#pragma unroll
        for (int i = 0; i < 4; ++i) { xh.u[i] = th_[tf][ks][i]; xl.u[i] = tl_[tf][ks][i]; }
        tva[tf] = xh.v; tvl[tf] = xl.v;
      }
#pragma unroll
      for (int cf = 0; cf < 4; ++cf) {
        const int row = cf * 16 + l15;
        const int off = row * 128 + ((ks * 64 + grp * 16) ^ ((row & 7) << 4));
        s16x8 gh = *(const s16x8*)(L + off);
        s16x8 gl = *(const s16x8*)(L + 8192 + off);
#pragma unroll
        for (int tf = 0; tf < 2; ++tf) {
          acc[cf][tf] = __builtin_amdgcn_mfma_f32_16x16x32_bf16(gh, tva[tf], acc[cf][tf], 0, 0, 0);
          acc[cf][tf] = __builtin_amdgcn_mfma_f32_16x16x32_bf16(gh, tvl[tf], acc[cf][tf], 0, 0, 0);
          acc[cf][tf] = __builtin_amdgcn_mfma_f32_16x16x32_bf16(gl, tva[tf], acc[cf][tf], 0, 0, 0);
        }
      }
    }
    // argmin: mask low 6 bits, embed within-chunk id; running top-2 via min/med3
    unsigned p1[2] = {u1[0], u1[1]};
#pragma unroll
    for (int cf = 0; cf < 4; ++cf) {
      const unsigned wbase = (unsigned)(cf * 16 + grp * 4);
#pragma unroll
      for (int tf = 0; tf < 2; ++tf) {
#pragma unroll
        for (int g = 0; g < 4; ++g) {
          unsigned vv = (__float_as_uint(acc[cf][tf][g]) & ~63u) | (wbase + (unsigned)g);
          u2[tf] = med3u(u1[tf], vv, u2[tf]);
          u1[tf] = u1[tf] < vv ? u1[tf] : vv;
        }
      }
    }
#pragma unroll
    for (int tf = 0; tf < 2; ++tf) if (u1[tf] != p1[tf]) c1[tf] = c;
    __syncthreads();
    if (more) {                                  // write next chunk after barrier
      char* Dst = smem + ((c + 1) & 1) * CHUNK_BYTES;
      uint4* d = (uint4*)Dst;
      d[tid] = ra; d[512 + tid] = rb;
      if (tid < 64) *(float*)(Dst + 16384 + tid * 4) = re2;
      __syncthreads();
    }
  }

  // ---- cross-lane finalize, outputs, near-tie flags, loss partial ----
  float lossacc = 0.f;
#pragma unroll
  for (int tf = 0; tf < 2; ++tf) {
    unsigned a1 = u1[tf], a2 = u2[tf]; int cc = c1[tf];
#pragma unroll
    for (int m = 16; m <= 32; m <<= 1) {
      unsigned b1 = __shfl_xor(a1, m);
      unsigned b2 = __shfl_xor(a2, m);
      int bc = __shfl_xor(cc, m);
      unsigned mx  = a1 > b1 ? a1 : b1;
      unsigned mn2 = a2 < b2 ? a2 : b2;
      a2 = mn2 < mx ? mn2 : mx;
      bool take = (b1 < a1) || (b1 == a1 && bc < cc);
      cc = take ? bc : cc;
      a1 = a1 < b1 ? a1 : b1;
    }
    const int code = cc * 64 + (int)(a1 & 63u);
    if (grp == 0) {
      const int tok = tb + tf * 16 + l15;
      idxw[tok] = code;
      fidx[tok] = (float)code;
      const float f1 = __uint_as_float(a1 & ~63u);
      const float f2 = __uint_as_float(a2 & ~63u);
      if (f2 - f1 < TAU) {
        int p = atomicAdd(cnt, 1);
        if (p < FLAG_CAP) flg[p] = tok;
      }
    }
    const float* q = emb + (size_t)code * 64;
#pragma unroll
    for (int ks = 0; ks < 2; ++ks) {
      const float4 qa = *(const float4*)(q + ks * 32 + grp * 8);
      const float4 qb = *(const float4*)(q + ks * 32 + grp * 8 + 4);
      float qv[8] = {qa.x, qa.y, qa.z, qa.w, qb.x, qb.y, qb.z, qb.w};
#pragma unroll
      for (int i = 0; i < 4; ++i) {
        unsigned hh = th_[tf][ks][i], ll = tl_[tf][ks][i];
        float t0 = bf2f(hh & 0xffffu) + bf2f(ll & 0xffffu);
        float t1 = bf2f(hh >> 16)     + bf2f(ll >> 16);
        float d0 = t0 - qv[2 * i], d1 = t1 - qv[2 * i + 1];
        lossacc = fmaf(d0, d0, lossacc);
        lossacc = fmaf(d1, d1, lossacc);
      }
    }
  }
#pragma unroll
  for (int m = 1; m < 64; m <<= 1) lossacc += __shfl_xor(lossacc, m);
  __syncthreads();
  float* ls = (float*)smem;
  if (lane == 0) ls[w] = lossacc;
  __syncthreads();
  if (tid == 0) {
    float s = 0.f;
#pragma unroll
    for (int i = 0; i < 8; ++i) s += ls[i];
    part[blockIdx.x] = s;
  }
}

// ---------------- Kernel R: f64 re-scan of near-tie tokens ---------------------
__global__ __launch_bounds__(256) void k_refine(const float* __restrict__ z,
    const float* __restrict__ emb, const float* __restrict__ pw, const float* __restrict__ pb,
    float* __restrict__ dout, char* __restrict__ ws)
{
  int cv = *(const int*)(ws + WS_CNT);
  if (cv > FLAG_CAP) cv = FLAG_CAP;
  if ((int)blockIdx.x >= cv) return;
  const int n = ((const int*)(ws + WS_FLAG))[blockIdx.x];
  const int b = n >> 15, r = n & (DHW - 1);
  const int tid = threadIdx.x;
  __shared__ double td[64];
  __shared__ double dsh[4]; __shared__ int ksh[4];
  if (tid < 64) {
    const float* zp = z + (size_t)b * 64 * DHW + r;
    const float* wr = pw + tid * 64;
    double a = (double)pb[tid];
    for (int c2 = 0; c2 < 64; ++c2) a += (double)wr[c2] * (double)zp[(size_t)c2 * DHW];
    td[tid] = a;
  }
  __syncthreads();
  double dmin = 1e300; int kmin = 0x7fffffff;
  for (int k0 = 0; k0 < KCB; k0 += 256) {
    const int k = k0 + tid;
    const float* e = emb + (size_t)k * 64;
    double d0 = 0.0, d1 = 0.0;
#pragma unroll 8
    for (int cch = 0; cch < 64; cch += 2) {
      double x0 = td[cch]     - (double)e[cch];
      double x1 = td[cch + 1] - (double)e[cch + 1];
      d0 = fma(x0, x0, d0); d1 = fma(x1, x1, d1);
    }
    double d = d0 + d1;
    if (d < dmin) { dmin = d; kmin = k; }     // ascending k -> first-occurrence
  }
  const int lane = tid & 63, wv = tid >> 6;
#pragma unroll
  for (int m = 1; m < 64; m <<= 1) {
    double od = __shfl_xor(dmin, m); int ok = __shfl_xor(kmin, m);
    if (od < dmin || (od == dmin && ok < kmin)) { dmin = od; kmin = ok; }
  }
  if (lane == 0) { dsh[wv] = dmin; ksh[wv] = kmin; }
  __syncthreads();
  if (tid == 0) {
    for (int i = 1; i < 4; ++i)
      if (dsh[i] < dmin || (dsh[i] == dmin && ksh[i] < kmin)) { dmin = dsh[i]; kmin = ksh[i]; }
    ((int*)(ws + WS_IDX))[n] = kmin;
    dout[OUT_ELEMS + 2 + n] = (float)kmin;
  }
}

// ---------------- Kernel D: post-conv (out = post_w@q + post_b) + loss final ---
__global__ __launch_bounds__(256) void k_post(const float* __restrict__ emb,
    const float* __restrict__ ow, const float* __restrict__ ob,
    float* __restrict__ dout, const char* __restrict__ ws)
{
  __shared__ float ps[256];
  const int v = blockIdx.x * 256 + threadIdx.x;
  const int b = v >> 15, r = v & (DHW - 1);
  const int code = ((const int*)(ws + WS_IDX))[v];
  const float* q = emb + (size_t)code * 64;
  float qr[64];
#pragma unroll
  for (int i = 0; i < 64; ++i) qr[i] = q[i];
  float* op = dout + (size_t)b * 64 * DHW + r;
  for (int o = 0; o < 64; ++o) {              // o uniform -> post_w row via s_load
    float a = ob[o];
    const float* wr = ow + o * 64;
#pragma unroll
    for (int cch = 0; cch < 64; ++cch) a = fmaf(wr[cch], qr[cch], a);
    op[(size_t)o * DHW] = a;                  // coalesced
  }
  if (blockIdx.x == 0) {
    ps[threadIdx.x] = ((const float*)(ws + WS_PART))[threadIdx.x];
    __syncthreads();
    if (threadIdx.x == 0) {
      float s = 0.f;
      for (int i = 0; i < 256; ++i) s += ps[i];   // fixed order: deterministic
      const float mean = s / 4194304.0f;
      dout[OUT_ELEMS]     = mean;   // codebook_loss
      dout[OUT_ELEMS + 1] = mean;   // commitment_loss (identical forward value)
    }
  }
}

extern "C" void kernel_launch(void* const* d_in, const int* in_sizes, int n_in,
                              void* d_out, int out_size, void* d_ws, size_t ws_size,
                              hipStream_t stream) {
  (void)in_sizes; (void)n_in; (void)out_size; (void)ws_size;
  const float* z   = (const float*)d_in[0];
  const float* emb = (const float*)d_in[1];
  const float* pw  = (const float*)d_in[2];
  const float* pb  = (const float*)d_in[3];
  const float* ow  = (const float*)d_in[4];
  const float* ob  = (const float*)d_in[5];
  float* out = (float*)d_out;
  char*  ws  = (char*)d_ws;

  hipLaunchKernelGGL(k_pre,    dim3(320),      dim3(256), 0, stream, z, emb, pw, pb, out, ws);
  hipLaunchKernelGGL(k_dist,   dim3(256),      dim3(512), 0, stream, emb, out, ws);
  hipLaunchKernelGGL(k_refine, dim3(FLAG_CAP), dim3(256), 0, stream, z, emb, pw, pb, out, ws);
  hipLaunchKernelGGL(k_post,   dim3(256),      dim3(256), 0, stream, emb, ow, ob, out, ws);
}